// Round 18
// baseline (196.621 us; speedup 1.0000x reference)
//
#include <hip/hip_runtime.h>
#include <math.h>

// SpectrumHead: rfft2(512x512) magnitude -> radial/angular histogram -> linear proj.
// B=64, C=3, H=512, W=512, W2=257, K_BINS=16, O_BINS=8, proj=64.
//
// Three-step 512 = 8x8x8 register FFT in WAVE-PRIVATE LDS segments (same-wave
// LDS ops are in-order on CDNA -> no barriers between transpose phases; only
// sched_barrier(0) pins compiler order). Swizzle: i ^ 9*(i>>6&7) in folded form.
//
// FFT8 core hand-specialized (r15). HW transcendentals (r17): v_sin/v_cos in
// revolutions (exact args), v_log, v_sqrt.
// r18: pass2 packs TWO adjacent columns per wave into ONE b64 LDS stream
// (uint2{bf16colA, bf16colB}) — 48 b64 ops vs 96 b32: ~-45% LDS-pipe cycles.
// Post-r17 arithmetic: LDS pipe (~17.9K cyc/CU-batch) ~= VALU (16.8K) were
// co-bottlenecks; r14 proved the 2-col STRUCTURE is perf-neutral, so any
// delta here is the pipe-work cut itself.
//
// F intermediate stored TRANSPOSED + bf16-packed: FT[ch_img][j][i] (uint32 per
// complex) -> pass2 column loads are contiguous 2KB runs, no cross-wave staging.
//
// Pass 0: transposed bin table binsT[j][i].
// Pass 1: TPB 1024 (16 waves = 16 row-pairs). Wave-private fp32 FFT + Hermitian
//         unpack + bf16 pack; ONE barrier; transposed write-out (128B i-runs).
// Pass 2: TPB 256, wave = columns (jA, jA+1) packed in b64 LDS. 8 cols/block.
// Pass 3: reduce 33 tile-partials per batch, normalize, h @ W.T + b.
//
// LAUNCH BOUNDS CALIBRATION (empirical, this toolchain): reported VGPR cap
// ~= 256/arg2 (r3:3->80, r4/6:6->40, r7:8->32, r8:4->56 no-spill). arg2=4 ->
// cap 64; pass2 peak est ~62 (no prefetch regs — r16 proved prefetch flat).

#define TPB0 256
#define TPB1 1024
#define TPB2 256
#define W2 257
#define NTILE 33           // pass2: 8 columns per block (2 per wave, packed)
#define CS 529             // pass1 per-wave segment stride, float2 units
#define CSU (2*CS)         // same stride in uint units (1058)
#define CSB2 513           // pass2 per-wave segment stride, uint2 units
#define FTS 512            // FT row stride in uints (2KB rows, line-aligned)
#define PI_F 3.14159265358979323846f
#define TWO_PI_F 6.28318530717958647692f
#define LN2_F 0.69314718055994530942f
#define SB() __builtin_amdgcn_sched_barrier(0)
#define PH(i) ((i) ^ ((((i) >> 6) & 7) * 9))

static constexpr int BR3[8] = {0,4,2,6,1,5,3,7};

__device__ __forceinline__ float2 cmulf(float2 a, float2 b) {
  return make_float2(a.x*b.x - a.y*b.y, a.x*b.y + a.y*b.x);
}
__device__ __forceinline__ float2 cadd(float2 a, float2 b) {
  return make_float2(a.x + b.x, a.y + b.y);
}
__device__ __forceinline__ float2 csub(float2 a, float2 b) {
  return make_float2(a.x - b.x, a.y - b.y);
}
__device__ __forceinline__ float2 cmulnegi(float2 a) {   // a * (-i)
  return make_float2(a.y, -a.x);
}
__device__ __forceinline__ unsigned bfpack(float2 v) {
  unsigned a = __float_as_uint(v.x) >> 16;
  unsigned b = __float_as_uint(v.y) & 0xFFFF0000u;
  return b | a;
}
__device__ __forceinline__ float2 bfunpack(unsigned p) {
  return make_float2(__uint_as_float(p << 16), __uint_as_float(p & 0xFFFF0000u));
}
// exp(2*pi*i*rev) via v_cos/v_sin (hardware takes REVOLUTIONS; |rev|<1 here).
__device__ __forceinline__ float2 wexp(float rev) {
  return make_float2(__builtin_amdgcn_cosf(rev), __builtin_amdgcn_sinf(rev));
}

// Specialized in-register DIT FFT8. Input bit-rev permuted; output natural.
// s0: w=1; s1: w in {1,-i}; s2: w in {1, C(1-i), -i, -C(1+i)}, C = sqrt(2)/2.
__device__ __forceinline__ void fft8(float2* z) {
  const float C = 0.70710678118654752f;
  float2 t;
  t = z[1]; z[1] = csub(z[0], t); z[0] = cadd(z[0], t);
  t = z[3]; z[3] = csub(z[2], t); z[2] = cadd(z[2], t);
  t = z[5]; z[5] = csub(z[4], t); z[4] = cadd(z[4], t);
  t = z[7]; z[7] = csub(z[6], t); z[6] = cadd(z[6], t);
  t = z[2];           z[2] = csub(z[0], t); z[0] = cadd(z[0], t);
  t = cmulnegi(z[3]); z[3] = csub(z[1], t); z[1] = cadd(z[1], t);
  t = z[6];           z[6] = csub(z[4], t); z[4] = cadd(z[4], t);
  t = cmulnegi(z[7]); z[7] = csub(z[5], t); z[5] = cadd(z[5], t);
  t = z[4];           z[4] = csub(z[0], t); z[0] = cadd(z[0], t);
  t = make_float2(C * (z[5].x + z[5].y), C * (z[5].y - z[5].x));
                      z[5] = csub(z[1], t); z[1] = cadd(z[1], t);
  t = cmulnegi(z[6]); z[6] = csub(z[2], t); z[2] = cadd(z[2], t);
  t = make_float2(C * (z[7].y - z[7].x), -C * (z[7].x + z[7].y));
                      z[7] = csub(z[3], t); z[3] = cadd(z[3], t);
}

// Apply chained twiddle powers: z[k] *= base^k, k = 1..7.
__device__ __forceinline__ void twiddle_chain(float2* z, float2 base) {
  float2 wk = base;
  #pragma unroll
  for (int k = 1; k < 8; ++k) {
    z[k] = cmulf(z[k], wk);
    if (k < 7) wk = cmulf(wk, base);
  }
}

__device__ __forceinline__ void get_bins(int i, int j, int& rb, int& ob) {
  // EXACT fp32 mirror of the reference — do not substitute fast math here.
  float yy = -1.0f + (float)i * (2.0f / 511.0f);
  float xx = (float)j * (1.0f / 256.0f);
  float rr = sqrtf(yy * yy + xx * xx);
  rr = fminf(rr, 1.0f - 1e-8f);
  float th = atan2f(yy, xx + 1e-9f) + 1.57079632679489662f;
  rb = (int)(rr * 16.0f);
  rb = rb < 0 ? 0 : (rb > 15 ? 15 : rb);
  ob = (int)((th / PI_F) * 8.0f);
  ob = ob < 0 ? 0 : (ob > 7 ? 7 : ob);
}

// Pass 0: TRANSPOSED bin table binsT[j][i] = rb | ob<<4. blockIdx.x = j.
__global__ __launch_bounds__(TPB0) void pass0_kernel(unsigned char* __restrict__ binsT) {
  int j = blockIdx.x;           // 0..256
  #pragma unroll
  for (int e = 0; e < 2; e++) {
    int i = threadIdx.x + e * 256;
    int rb, ob;
    get_bins(i, j, rb, ob);
    binsT[(size_t)j * 512 + i] = (unsigned char)(rb | (ob << 4));
  }
}

// Pass 1: blockIdx.x = ic_local*16 + segblk. Wave wv = row-pair
// rp = segblk*16 + wv (rows 2rp, 2rp+1 packed as one complex 512-pt FFT).
// Output: FT[ic_local][j][i] bf16-packed, i-chunk [segblk*32, +32).
__global__ __launch_bounds__(TPB1, 4) void pass1_kernel(
    const float* __restrict__ x, unsigned* __restrict__ FT, int ic0) {
  __shared__ float2 xbuf[16 * CS];       // 67.7 KB: 16 wave-private segments
  int t = threadIdx.x;
  int segblk = blockIdx.x & 15;
  int ic_local = blockIdx.x >> 4;
  int wv = t >> 6;
  int u = t & 63;
  int rp = segblk * 16 + wv;
  const float* row0 = x + (((size_t)(ic0 + ic_local)) * 512 + (size_t)rp * 2) * 512;
  const float* row1 = row0 + 512;
  float2* seg = xbuf + wv * CS;
  unsigned* useg = (unsigned*)xbuf + wv * CSU;

  const int ul = u & 7, wq = u >> 3;
  const int x9 = 9 * wq, b64 = 64 * wq;

  float2 w1  = wexp((float)u  * (-1.0f / 512.0f));   // W512^-u
  float2 w64 = wexp((float)ul * (-1.0f / 64.0f));    // W64^-ul

  // step 1: FFT8 over m, twiddle W512^(u*k3) via chain
  float2 z[8];
  #pragma unroll
  for (int m = 0; m < 8; ++m)
    z[BR3[m]] = make_float2(row0[u + 64 * m], row1[u + 64 * m]);
  fft8(z);
  twiddle_chain(z, w1);
  SB();
  #pragma unroll
  for (int k3 = 0; k3 < 8; ++k3) seg[(u ^ (9 * k3)) + 64 * k3] = z[k3];   // L1[k3][u]
  SB();
  // step 2: FFT8 over g2, twiddle W64^(ul*K2) via chain
  #pragma unroll
  for (int g2 = 0; g2 < 8; ++g2) z[BR3[g2]] = seg[((ul + 8 * g2) ^ x9) + b64];
  fft8(z);
  twiddle_chain(z, w64);
  SB();
  #pragma unroll
  for (int K2 = 0; K2 < 8; ++K2) seg[((K2 * 8 + ul) ^ x9) + b64] = z[K2]; // L2
  SB();
  // step 3: FFT8 over g1 -> Z[wq + 8ul + 64K1]
  #pragma unroll
  for (int gg = 0; gg < 8; ++gg) z[BR3[gg]] = seg[((ul * 8 + gg) ^ x9) + b64];
  fft8(z);
  SB();
  #pragma unroll
  for (int K1 = 0; K1 < 8; ++K1)
    seg[((wq + 8 * ul) ^ (9 * K1)) + 64 * K1] = z[K1];                    // Z natural, swizzled
  SB();
  // Hermitian unpack (fp32) + bf16 pack; stash as uints in own segment.
  unsigned p0[4], p1[4];
  #pragma unroll
  for (int e = 0; e < 4; ++e) {
    int k = u + 64 * e;
    int km = (512 - k) & 511;
    float2 zk = seg[PH(k)];
    float2 zm = seg[PH(km)];
    p0[e] = bfpack(make_float2(0.5f * (zk.x + zm.x),  0.5f * (zk.y - zm.y)));
    p1[e] = bfpack(make_float2(0.5f * (zk.y + zm.y), -0.5f * (zk.x - zm.x)));
  }
  unsigned p0n = 0, p1n = 0;
  if (u == 0) {
    float2 zk = seg[PH(256)];            // Nyquist (self-paired)
    p0n = bfpack(make_float2(zk.x, 0.0f));
    p1n = bfpack(make_float2(zk.y, 0.0f));
  }
  SB();
  #pragma unroll
  for (int e = 0; e < 4; ++e) {
    int k = u + 64 * e;
    useg[k] = p0[e];                     // row 2rp   spectrum at [k]
    useg[257 + k] = p1[e];               // row 2rp+1 spectrum at [257+k]
  }
  if (u == 0) { useg[256] = p0n; useg[513] = p1n; }
  __syncthreads();

  // transposed write-out: for each j, 32 consecutive i (128B run).
  unsigned* FTc = FT + (size_t)ic_local * (W2 * FTS);
  int i0 = segblk * 32;
  const unsigned* xb = (const unsigned*)xbuf;
  #pragma unroll
  for (int it = 0; it < 9; ++it) {
    int idx = t + TPB1 * it;
    if (idx < W2 * 32) {
      int j = idx >> 5;
      int il = idx & 31;                 // i_local = 2*pair + hi
      unsigned v = xb[(il >> 1) * CSU + (il & 1) * 257 + j];
      FTc[(size_t)j * FTS + i0 + il] = v;
    }
  }
}

// Pass 2: blockIdx.x = b_local*NTILE + tile. Wave wv owns adjacent columns
// jA = tile*8 + 2*wv, jB = jA+1, PACKED as uint2{bf16A, bf16B} in ONE b64 LDS
// stream (halves LDS-pipe ops vs two b32 streams). Contiguous 2KB column loads;
// wave-private; zero staging barriers. HW transcendentals.
__global__ __launch_bounds__(TPB2, 4) void pass2_kernel(
    const unsigned* __restrict__ FT, const unsigned char* __restrict__ binsT,
    float* __restrict__ partial, int b0) {
  __shared__ uint2 xbuf[4 * CSB2];       // 16.4 KB: 4 wave-private b64 segments
  __shared__ float hist[128];            // combined bins: rb + 16*ob
  int t = threadIdx.x;
  int tile = blockIdx.x % NTILE;
  int b_local = blockIdx.x / NTILE;
  int wv = t >> 6;
  int u = t & 63;
  int jA = tile * 8 + 2 * wv;
  int jB = jA + 1;
  bool validA = (jA < W2), validB = (jB < W2);
  int jAc = validA ? jA : (W2 - 1);      // clamped (valid memory, hist-skipped)
  int jBc = validB ? jB : (W2 - 1);
  uint2* seg = xbuf + wv * CSB2;
  const int ul = u & 7, wq = u >> 3;
  const int x9 = 9 * wq, b64 = 64 * wq;

  if (t < 128) hist[t] = 0.0f;
  __syncthreads();

  float2 w1  = wexp((float)u  * (-1.0f / 512.0f));
  float2 w64 = wexp((float)ul * (-1.0f / 64.0f));

  float magA[8], magB[8];
  #pragma unroll
  for (int q = 0; q < 8; ++q) { magA[q] = 0.0f; magB[q] = 0.0f; }

  for (int c = 0; c < 3; ++c) {
    const unsigned* base = FT + (size_t)(b_local * 3 + c) * W2 * FTS;
    const unsigned* colA = base + (size_t)jAc * FTS;
    const unsigned* colB = base + (size_t)jBc * FTS;
    float2 zA[8], zB[8];
    #pragma unroll
    for (int m = 0; m < 8; ++m) zA[BR3[m]] = bfunpack(colA[u + 64 * m]);
    #pragma unroll
    for (int m = 0; m < 8; ++m) zB[BR3[m]] = bfunpack(colB[u + 64 * m]);
    fft8(zA);
    fft8(zB);
    twiddle_chain(zA, w1);
    twiddle_chain(zB, w1);
    SB();
    #pragma unroll
    for (int k3 = 0; k3 < 8; ++k3)
      seg[(u ^ (9 * k3)) + 64 * k3] = make_uint2(bfpack(zA[k3]), bfpack(zB[k3]));
    SB();
    #pragma unroll
    for (int g2 = 0; g2 < 8; ++g2) {
      uint2 v = seg[((ul + 8 * g2) ^ x9) + b64];
      zA[BR3[g2]] = bfunpack(v.x);
      zB[BR3[g2]] = bfunpack(v.y);
    }
    fft8(zA);
    fft8(zB);
    twiddle_chain(zA, w64);
    twiddle_chain(zB, w64);
    SB();
    #pragma unroll
    for (int K2 = 0; K2 < 8; ++K2)
      seg[((K2 * 8 + ul) ^ x9) + b64] = make_uint2(bfpack(zA[K2]), bfpack(zB[K2]));
    SB();
    #pragma unroll
    for (int gg = 0; gg < 8; ++gg) {
      uint2 v = seg[((ul * 8 + gg) ^ x9) + b64];
      zA[BR3[gg]] = bfunpack(v.x);
      zB[BR3[gg]] = bfunpack(v.y);
    }
    fft8(zA);
    fft8(zB);
    #pragma unroll
    for (int K1 = 0; K1 < 8; ++K1) {
      magA[K1] += __builtin_amdgcn_sqrtf(zA[K1].x * zA[K1].x + zA[K1].y * zA[K1].y);
      magB[K1] += __builtin_amdgcn_sqrtf(zB[K1].x * zB[K1].x + zB[K1].y * zB[K1].y);
    }
    SB();                                // seg reads done before next channel
  }

  if (validA) {
    const unsigned char* bj = binsT + (size_t)jA * 512;
    #pragma unroll
    for (int K1 = 0; K1 < 8; ++K1) {
      int row = wq + 8 * ul + 64 * K1;
      // scale: ortho (1/512) * channel mean (1/3) = 1/1536
      float m = __builtin_amdgcn_logf(1.0f + magA[K1] * (1.0f / 1536.0f)) * LN2_F;
      atomicAdd(&hist[bj[row]], m);
    }
  }
  if (validB) {
    const unsigned char* bj = binsT + (size_t)jB * 512;
    #pragma unroll
    for (int K1 = 0; K1 < 8; ++K1) {
      int row = wq + 8 * ul + 64 * K1;
      float m = __builtin_amdgcn_logf(1.0f + magB[K1] * (1.0f / 1536.0f)) * LN2_F;
      atomicAdd(&hist[bj[row]], m);
    }
  }
  __syncthreads();

  // fold 128 combined bins -> 16 radial + 8 angular partials
  int b = b0 + b_local;
  if (t < 16) {
    float s = 0.0f;
    #pragma unroll
    for (int ob = 0; ob < 8; ++ob) s += hist[t + 16 * ob];
    partial[((size_t)b * NTILE + tile) * 24 + t] = s;
  } else if (t < 24) {
    float s = 0.0f;
    int ob = t - 16;
    #pragma unroll
    for (int rb = 0; rb < 16; ++rb) s += hist[rb + 16 * ob];
    partial[((size_t)b * NTILE + tile) * 24 + t] = s;
  }
}

// Pass 3: one block per batch. Reduce NTILE partials, normalize, project.
__global__ __launch_bounds__(TPB0) void pass3_kernel(
    const float* __restrict__ partial, const float* __restrict__ W,
    const float* __restrict__ bias, float* __restrict__ out) {
  __shared__ float h[24];
  __shared__ float hn[24];
  int b = blockIdx.x;
  int t = threadIdx.x;
  if (t < 24) {
    float s = 0.0f;
    for (int tile = 0; tile < NTILE; tile++)
      s += partial[((size_t)b * NTILE + tile) * 24 + t];
    h[t] = s;
  }
  __syncthreads();
  if (t == 0) {
    float rs = 0.0f, as = 0.0f;
    for (int k = 0; k < 16; k++) rs += h[k];
    for (int k = 16; k < 24; k++) as += h[k];
    for (int k = 0; k < 16; k++) hn[k] = h[k] / (rs + 1e-6f);
    for (int k = 16; k < 24; k++) hn[k] = h[k] / (as + 1e-6f);
  }
  __syncthreads();
  if (t < 64) {
    float acc = bias[t];
    #pragma unroll
    for (int k = 0; k < 24; k++) acc += hn[k] * W[t * 24 + k];
    out[b * 64 + t] = acc;
  }
}

extern "C" void kernel_launch(void* const* d_in, const int* in_sizes, int n_in,
                              void* d_out, int out_size, void* d_ws, size_t ws_size,
                              hipStream_t stream) {
  const float* x    = (const float*)d_in[0];   // [64,3,512,512]
  const float* W    = (const float*)d_in[1];   // [64,24]
  const float* bias = (const float*)d_in[2];   // [64]
  float* out = (float*)d_out;                  // [64,64]

  // ws layout: tile partials | transposed bin table | bf16 F^T
  const size_t partial_bytes = (size_t)64 * NTILE * 24 * sizeof(float);
  size_t off_bins = (partial_bytes + 255) & ~(size_t)255;
  const size_t bins_bytes = (size_t)W2 * 512;
  size_t off_F = ((off_bins + bins_bytes) + 255) & ~(size_t)255;

  float* partial = (float*)d_ws;
  unsigned char* binsT = (unsigned char*)d_ws + off_bins;
  unsigned* FT = (unsigned*)((char*)d_ws + off_F);

  const size_t per_batch = (size_t)3 * W2 * FTS * sizeof(unsigned);  // 1.58 MB
  size_t avail = ws_size > off_F ? ws_size - off_F : 0;
  int bpc = (int)(avail / per_batch);
  if (bpc < 1) bpc = 1;
  if (bpc > 64) bpc = 64;

  pass0_kernel<<<W2, TPB0, 0, stream>>>(binsT);

  for (int b0 = 0; b0 < 64; b0 += bpc) {
    int nb = (64 - b0) < bpc ? (64 - b0) : bpc;
    pass1_kernel<<<nb * 3 * 16, TPB1, 0, stream>>>(x, FT, b0 * 3);
    pass2_kernel<<<nb * NTILE, TPB2, 0, stream>>>(FT, binsT, partial, b0);
  }
  pass3_kernel<<<64, TPB0, 0, stream>>>(partial, W, bias, out);
}

// Round 19
// 149.083 us; speedup vs baseline: 1.3189x; 1.3189x over previous
//
#include <hip/hip_runtime.h>
#include <math.h>

// SpectrumHead: rfft2(512x512) magnitude -> radial/angular histogram -> linear proj.
// B=64, C=3, H=512, W=512, W2=257, K_BINS=16, O_BINS=8, proj=64.
//
// == r19 = REVERT to r17 (149.3 us best-known). r18's 2-col b64 pack spilled:
// VGPR pinned at cap 64, WRITE_SIZE 101 MB of scratch, 197 us. The 2-col state
// (64 regs) + mags (16) cannot fit the 64-reg envelope; arg2=3 (cap 80) would
// drop TLP to 3 blocks/CU which history (r3/r4) says loses more.
//
// Three-step 512 = 8x8x8 register FFT in WAVE-PRIVATE LDS segments (same-wave
// LDS ops are in-order on CDNA -> no barriers between transpose phases; only
// sched_barrier(0) pins compiler order). Swizzle PH(i) = i ^ 9*(i>>6&7), written
// in folded form (C ^ 9q) + 64q. All FFT phases at the wave64 LDS bank floor.
//
// FFT8 core hand-specialized (r15): only 4 real mults per FFT8 (~56 VALU).
// r16: channel-loop prefetch (flat — kept, harmless).
// r17: libm -> hardware transcendentals: sincosf -> v_sin/v_cos (args are
//      EXACT revolutions -u/512, -ul/64 — no range reduction); log1pf(x) ->
//      v_log_f32(1+x)*ln2; sqrtf -> v_sqrt_f32. get_bins (pass0) byte-identical
//      to the reference — bin INDICES must match fp32 exactly.
//
// F intermediate stored TRANSPOSED + bf16-packed: FT[ch_img][j][i] (uint32 per
// complex) -> pass2 column loads are contiguous 2KB runs, no cross-wave staging.
//
// Pass 0: transposed bin table binsT[j][i].
// Pass 1: TPB 1024 (16 waves = 16 row-pairs). Wave-private FFT + Hermitian
//         unpack + bf16 pack; ONE barrier; transposed write-out (128B i-runs).
// Pass 2: TPB 256, wave = one column j. bf16 LDS segments.
// Pass 3: reduce 65 tile-partials per batch, normalize, h @ W.T + b.
//
// LAUNCH BOUNDS CALIBRATION (empirical, this toolchain): reported VGPR cap
// ~= 256/arg2 (r3:3->80, r4/6:6->40, r7:8->32, r8:4->56 no-spill). arg2=4 ->
// cap 64.

#define TPB0 256
#define TPB1 1024
#define TPB2 256
#define W2 257
#define NTILE 65           // pass2: 4 columns per block
#define CS 529             // pass1 per-wave segment stride, float2 units
#define CSU (2*CS)         // same stride in uint units (1058)
#define CSB 513            // pass2 per-col segment stride, uint units (==1 mod 32)
#define FTS 512            // FT row stride in uints (2KB rows, line-aligned)
#define PI_F 3.14159265358979323846f
#define TWO_PI_F 6.28318530717958647692f
#define LN2_F 0.69314718055994530942f
#define SB() __builtin_amdgcn_sched_barrier(0)
#define PH(i) ((i) ^ ((((i) >> 6) & 7) * 9))

static constexpr int BR3[8] = {0,4,2,6,1,5,3,7};

__device__ __forceinline__ float2 cmulf(float2 a, float2 b) {
  return make_float2(a.x*b.x - a.y*b.y, a.x*b.y + a.y*b.x);
}
__device__ __forceinline__ float2 cadd(float2 a, float2 b) {
  return make_float2(a.x + b.x, a.y + b.y);
}
__device__ __forceinline__ float2 csub(float2 a, float2 b) {
  return make_float2(a.x - b.x, a.y - b.y);
}
__device__ __forceinline__ float2 cmulnegi(float2 a) {   // a * (-i)
  return make_float2(a.y, -a.x);
}
__device__ __forceinline__ unsigned bfpack(float2 v) {
  unsigned a = __float_as_uint(v.x) >> 16;
  unsigned b = __float_as_uint(v.y) & 0xFFFF0000u;
  return b | a;
}
__device__ __forceinline__ float2 bfunpack(unsigned p) {
  return make_float2(__uint_as_float(p << 16), __uint_as_float(p & 0xFFFF0000u));
}
// exp(2*pi*i*rev) via v_cos/v_sin (hardware takes REVOLUTIONS; |rev|<1 here,
// no reduction needed; ~1ulp, fed into bf16-quantized pipeline).
__device__ __forceinline__ float2 wexp(float rev) {
  return make_float2(__builtin_amdgcn_cosf(rev), __builtin_amdgcn_sinf(rev));
}

// Specialized in-register DIT FFT8. Input bit-rev permuted; output natural.
// Generic radix-2 loop with stage twiddles constant-folded:
// s0: w=1; s1: w in {1,-i}; s2: w in {1, C(1-i), -i, -C(1+i)}, C = sqrt(2)/2.
__device__ __forceinline__ void fft8(float2* z) {
  const float C = 0.70710678118654752f;
  float2 t;
  t = z[1]; z[1] = csub(z[0], t); z[0] = cadd(z[0], t);
  t = z[3]; z[3] = csub(z[2], t); z[2] = cadd(z[2], t);
  t = z[5]; z[5] = csub(z[4], t); z[4] = cadd(z[4], t);
  t = z[7]; z[7] = csub(z[6], t); z[6] = cadd(z[6], t);
  t = z[2];           z[2] = csub(z[0], t); z[0] = cadd(z[0], t);
  t = cmulnegi(z[3]); z[3] = csub(z[1], t); z[1] = cadd(z[1], t);
  t = z[6];           z[6] = csub(z[4], t); z[4] = cadd(z[4], t);
  t = cmulnegi(z[7]); z[7] = csub(z[5], t); z[5] = cadd(z[5], t);
  t = z[4];           z[4] = csub(z[0], t); z[0] = cadd(z[0], t);
  t = make_float2(C * (z[5].x + z[5].y), C * (z[5].y - z[5].x));
                      z[5] = csub(z[1], t); z[1] = cadd(z[1], t);
  t = cmulnegi(z[6]); z[6] = csub(z[2], t); z[2] = cadd(z[2], t);
  t = make_float2(C * (z[7].y - z[7].x), -C * (z[7].x + z[7].y));
                      z[7] = csub(z[3], t); z[3] = cadd(z[3], t);
}

// Apply chained twiddle powers: z[k] *= base^k, k = 1..7.
__device__ __forceinline__ void twiddle_chain(float2* z, float2 base) {
  float2 wk = base;
  #pragma unroll
  for (int k = 1; k < 8; ++k) {
    z[k] = cmulf(z[k], wk);
    if (k < 7) wk = cmulf(wk, base);
  }
}

__device__ __forceinline__ void get_bins(int i, int j, int& rb, int& ob) {
  // EXACT fp32 mirror of the reference — do not substitute fast math here
  // (bin indices flip at boundaries).
  float yy = -1.0f + (float)i * (2.0f / 511.0f);
  float xx = (float)j * (1.0f / 256.0f);
  float rr = sqrtf(yy * yy + xx * xx);
  rr = fminf(rr, 1.0f - 1e-8f);
  float th = atan2f(yy, xx + 1e-9f) + 1.57079632679489662f;
  rb = (int)(rr * 16.0f);
  rb = rb < 0 ? 0 : (rb > 15 ? 15 : rb);
  ob = (int)((th / PI_F) * 8.0f);
  ob = ob < 0 ? 0 : (ob > 7 ? 7 : ob);
}

// Pass 0: TRANSPOSED bin table binsT[j][i] = rb | ob<<4. blockIdx.x = j.
__global__ __launch_bounds__(TPB0) void pass0_kernel(unsigned char* __restrict__ binsT) {
  int j = blockIdx.x;           // 0..256
  #pragma unroll
  for (int e = 0; e < 2; e++) {
    int i = threadIdx.x + e * 256;
    int rb, ob;
    get_bins(i, j, rb, ob);
    binsT[(size_t)j * 512 + i] = (unsigned char)(rb | (ob << 4));
  }
}

// Pass 1: blockIdx.x = ic_local*16 + segblk. Wave wv = row-pair
// rp = segblk*16 + wv (rows 2rp, 2rp+1 packed as one complex 512-pt FFT).
// Output: FT[ic_local][j][i] bf16-packed, i-chunk [segblk*32, +32).
__global__ __launch_bounds__(TPB1, 4) void pass1_kernel(
    const float* __restrict__ x, unsigned* __restrict__ FT, int ic0) {
  __shared__ float2 xbuf[16 * CS];       // 67.7 KB: 16 wave-private segments
  int t = threadIdx.x;
  int segblk = blockIdx.x & 15;
  int ic_local = blockIdx.x >> 4;
  int wv = t >> 6;
  int u = t & 63;
  int rp = segblk * 16 + wv;
  const float* row0 = x + (((size_t)(ic0 + ic_local)) * 512 + (size_t)rp * 2) * 512;
  const float* row1 = row0 + 512;
  float2* seg = xbuf + wv * CS;
  unsigned* useg = (unsigned*)xbuf + wv * CSU;

  const int ul = u & 7, wq = u >> 3;
  const int x9 = 9 * wq, b64 = 64 * wq;

  float2 w1  = wexp((float)u  * (-1.0f / 512.0f));   // W512^-u
  float2 w64 = wexp((float)ul * (-1.0f / 64.0f));    // W64^-ul

  // step 1: FFT8 over m, twiddle W512^(u*k3) via chain
  float2 z[8];
  #pragma unroll
  for (int m = 0; m < 8; ++m)
    z[BR3[m]] = make_float2(row0[u + 64 * m], row1[u + 64 * m]);
  fft8(z);
  twiddle_chain(z, w1);
  SB();
  #pragma unroll
  for (int k3 = 0; k3 < 8; ++k3) seg[(u ^ (9 * k3)) + 64 * k3] = z[k3];   // L1[k3][u]
  SB();
  // step 2: FFT8 over g2, twiddle W64^(ul*K2) via chain
  #pragma unroll
  for (int g2 = 0; g2 < 8; ++g2) z[BR3[g2]] = seg[((ul + 8 * g2) ^ x9) + b64];
  fft8(z);
  twiddle_chain(z, w64);
  SB();
  #pragma unroll
  for (int K2 = 0; K2 < 8; ++K2) seg[((K2 * 8 + ul) ^ x9) + b64] = z[K2]; // L2
  SB();
  // step 3: FFT8 over g1 -> Z[wq + 8ul + 64K1]
  #pragma unroll
  for (int gg = 0; gg < 8; ++gg) z[BR3[gg]] = seg[((ul * 8 + gg) ^ x9) + b64];
  fft8(z);
  SB();
  #pragma unroll
  for (int K1 = 0; K1 < 8; ++K1)
    seg[((wq + 8 * ul) ^ (9 * K1)) + 64 * K1] = z[K1];                    // Z natural, swizzled
  SB();
  // Hermitian unpack (fp32) + bf16 pack; stash as uints in own segment.
  unsigned p0[4], p1[4];
  #pragma unroll
  for (int e = 0; e < 4; ++e) {
    int k = u + 64 * e;
    int km = (512 - k) & 511;
    float2 zk = seg[PH(k)];
    float2 zm = seg[PH(km)];
    p0[e] = bfpack(make_float2(0.5f * (zk.x + zm.x),  0.5f * (zk.y - zm.y)));
    p1[e] = bfpack(make_float2(0.5f * (zk.y + zm.y), -0.5f * (zk.x - zm.x)));
  }
  unsigned p0n = 0, p1n = 0;
  if (u == 0) {
    float2 zk = seg[PH(256)];            // Nyquist (self-paired)
    p0n = bfpack(make_float2(zk.x, 0.0f));
    p1n = bfpack(make_float2(zk.y, 0.0f));
  }
  SB();
  #pragma unroll
  for (int e = 0; e < 4; ++e) {
    int k = u + 64 * e;
    useg[k] = p0[e];                     // row 2rp   spectrum at [k]
    useg[257 + k] = p1[e];               // row 2rp+1 spectrum at [257+k]
  }
  if (u == 0) { useg[256] = p0n; useg[513] = p1n; }
  __syncthreads();

  // transposed write-out: for each j, 32 consecutive i (128B run).
  unsigned* FTc = FT + (size_t)ic_local * (W2 * FTS);
  int i0 = segblk * 32;
  const unsigned* xb = (const unsigned*)xbuf;
  #pragma unroll
  for (int it = 0; it < 9; ++it) {
    int idx = t + TPB1 * it;
    if (idx < W2 * 32) {
      int j = idx >> 5;
      int il = idx & 31;                 // i_local = 2*pair + hi
      unsigned v = xb[(il >> 1) * CSU + (il & 1) * 257 + j];
      FTc[(size_t)j * FTS + i0 + il] = v;
    }
  }
}

// Pass 2: blockIdx.x = b_local*NTILE + tile. Wave wv owns column j = tile*4+wv.
// Contiguous 2KB column loads; wave-private bf16 FFT; zero staging barriers.
// Channel loop software-pipelined (prefetch regs). HW transcendentals (r17).
__global__ __launch_bounds__(TPB2, 4) void pass2_kernel(
    const unsigned* __restrict__ FT, const unsigned char* __restrict__ binsT,
    float* __restrict__ partial, int b0) {
  __shared__ unsigned xbuf[4 * CSB];     // 8.2 KB: 4 wave-private segments
  __shared__ float hist[128];            // combined bins: rb + 16*ob
  int t = threadIdx.x;
  int tile = blockIdx.x % NTILE;
  int b_local = blockIdx.x / NTILE;
  int wv = t >> 6;
  int u = t & 63;
  int j = tile * 4 + wv;
  bool jvalid = (j < W2);
  unsigned* seg = xbuf + wv * CSB;
  const int ul = u & 7, wq = u >> 3;
  const int x9 = 9 * wq, b64 = 64 * wq;

  if (t < 128) hist[t] = 0.0f;
  __syncthreads();

  if (jvalid) {
    float2 w1  = wexp((float)u  * (-1.0f / 512.0f));
    float2 w64 = wexp((float)ul * (-1.0f / 64.0f));

    float mag[8];
    #pragma unroll
    for (int q = 0; q < 8; ++q) mag[q] = 0.0f;

    const unsigned* col0 = FT + ((size_t)(b_local * 3 + 0) * W2 + j) * FTS;
    const unsigned* col1 = col0 + (size_t)W2 * FTS;
    const unsigned* col2 = col1 + (size_t)W2 * FTS;

    // prefetch channel 0
    unsigned pk[8];
    #pragma unroll
    for (int m = 0; m < 8; ++m) pk[m] = col0[u + 64 * m];

    #pragma unroll
    for (int c = 0; c < 3; ++c) {
      float2 z[8];
      #pragma unroll
      for (int m = 0; m < 8; ++m) z[BR3[m]] = bfunpack(pk[m]);
      // issue next channel's loads NOW — latency hides under the FFT chain
      if (c == 0) {
        #pragma unroll
        for (int m = 0; m < 8; ++m) pk[m] = col1[u + 64 * m];
      } else if (c == 1) {
        #pragma unroll
        for (int m = 0; m < 8; ++m) pk[m] = col2[u + 64 * m];
      }
      fft8(z);
      twiddle_chain(z, w1);
      SB();
      #pragma unroll
      for (int k3 = 0; k3 < 8; ++k3) seg[(u ^ (9 * k3)) + 64 * k3] = bfpack(z[k3]);
      SB();
      #pragma unroll
      for (int g2 = 0; g2 < 8; ++g2) z[BR3[g2]] = bfunpack(seg[((ul + 8 * g2) ^ x9) + b64]);
      fft8(z);
      twiddle_chain(z, w64);
      SB();
      #pragma unroll
      for (int K2 = 0; K2 < 8; ++K2) seg[((K2 * 8 + ul) ^ x9) + b64] = bfpack(z[K2]);
      SB();
      #pragma unroll
      for (int gg = 0; gg < 8; ++gg) z[BR3[gg]] = bfunpack(seg[((ul * 8 + gg) ^ x9) + b64]);
      fft8(z);
      #pragma unroll
      for (int K1 = 0; K1 < 8; ++K1)
        mag[K1] += __builtin_amdgcn_sqrtf(z[K1].x * z[K1].x + z[K1].y * z[K1].y);
      SB();                              // seg reads done before next channel's writes
    }

    const unsigned char* bj = binsT + (size_t)j * 512;
    #pragma unroll
    for (int K1 = 0; K1 < 8; ++K1) {
      int row = wq + 8 * ul + 64 * K1;
      int code = bj[row];                // coalesced 64B run per K1
      // scale: ortho (1/512) * channel mean (1/3) = 1/1536
      // ln(1+x) = log2(1+x)*ln2 via v_log_f32 (~1ulp; bins sum ~1e5 then
      // normalize — absolute error negligible vs 2.77e-3 threshold)
      float m = __builtin_amdgcn_logf(1.0f + mag[K1] * (1.0f / 1536.0f)) * LN2_F;
      atomicAdd(&hist[code], m);
    }
  }
  __syncthreads();

  // fold 128 combined bins -> 16 radial + 8 angular partials
  int b = b0 + b_local;
  if (t < 16) {
    float s = 0.0f;
    #pragma unroll
    for (int ob = 0; ob < 8; ++ob) s += hist[t + 16 * ob];
    partial[((size_t)b * NTILE + tile) * 24 + t] = s;
  } else if (t < 24) {
    float s = 0.0f;
    int ob = t - 16;
    #pragma unroll
    for (int rb = 0; rb < 16; ++rb) s += hist[rb + 16 * ob];
    partial[((size_t)b * NTILE + tile) * 24 + t] = s;
  }
}

// Pass 3: one block per batch. Reduce NTILE partials, normalize, project.
__global__ __launch_bounds__(TPB0) void pass3_kernel(
    const float* __restrict__ partial, const float* __restrict__ W,
    const float* __restrict__ bias, float* __restrict__ out) {
  __shared__ float h[24];
  __shared__ float hn[24];
  int b = blockIdx.x;
  int t = threadIdx.x;
  if (t < 24) {
    float s = 0.0f;
    for (int tile = 0; tile < NTILE; tile++)
      s += partial[((size_t)b * NTILE + tile) * 24 + t];
    h[t] = s;
  }
  __syncthreads();
  if (t == 0) {
    float rs = 0.0f, as = 0.0f;
    for (int k = 0; k < 16; k++) rs += h[k];
    for (int k = 16; k < 24; k++) as += h[k];
    for (int k = 0; k < 16; k++) hn[k] = h[k] / (rs + 1e-6f);
    for (int k = 16; k < 24; k++) hn[k] = h[k] / (as + 1e-6f);
  }
  __syncthreads();
  if (t < 64) {
    float acc = bias[t];
    #pragma unroll
    for (int k = 0; k < 24; k++) acc += hn[k] * W[t * 24 + k];
    out[b * 64 + t] = acc;
  }
}

extern "C" void kernel_launch(void* const* d_in, const int* in_sizes, int n_in,
                              void* d_out, int out_size, void* d_ws, size_t ws_size,
                              hipStream_t stream) {
  const float* x    = (const float*)d_in[0];   // [64,3,512,512]
  const float* W    = (const float*)d_in[1];   // [64,24]
  const float* bias = (const float*)d_in[2];   // [64]
  float* out = (float*)d_out;                  // [64,64]

  // ws layout: tile partials | transposed bin table | bf16 F^T
  const size_t partial_bytes = (size_t)64 * NTILE * 24 * sizeof(float);
  size_t off_bins = (partial_bytes + 255) & ~(size_t)255;
  const size_t bins_bytes = (size_t)W2 * 512;
  size_t off_F = ((off_bins + bins_bytes) + 255) & ~(size_t)255;

  float* partial = (float*)d_ws;
  unsigned char* binsT = (unsigned char*)d_ws + off_bins;
  unsigned* FT = (unsigned*)((char*)d_ws + off_F);

  const size_t per_batch = (size_t)3 * W2 * FTS * sizeof(unsigned);  // 1.58 MB
  size_t avail = ws_size > off_F ? ws_size - off_F : 0;
  int bpc = (int)(avail / per_batch);
  if (bpc < 1) bpc = 1;
  if (bpc > 64) bpc = 64;

  pass0_kernel<<<W2, TPB0, 0, stream>>>(binsT);

  for (int b0 = 0; b0 < 64; b0 += bpc) {
    int nb = (64 - b0) < bpc ? (64 - b0) : bpc;
    pass1_kernel<<<nb * 3 * 16, TPB1, 0, stream>>>(x, FT, b0 * 3);
    pass2_kernel<<<nb * NTILE, TPB2, 0, stream>>>(FT, binsT, partial, b0);
  }
  pass3_kernel<<<64, TPB0, 0, stream>>>(partial, W, bias, out);
}